// Round 20
// baseline (1175.059 us; speedup 1.0000x reference)
//
#include <hip/hip_runtime.h>
#include <stdint.h>
#include <math.h>

#define NH 4
#define BS 32
#define QS 4096
#define NTOK 4097
#define DIM 64
#define NC 32
#define CROWS 129

// --- contraction-proof f32 ops (hipcc defaults to -ffp-contract=fast) ---
__device__ __forceinline__ float mulf(float a, float b) { float r = a * b; asm volatile("" : "+v"(r)); return r; }
__device__ __forceinline__ float addf(float a, float b) { float r = a + b; asm volatile("" : "+v"(r)); return r; }
__device__ __forceinline__ float subf(float a, float b) { float r = a - b; asm volatile("" : "+v"(r)); return r; }
__device__ __forceinline__ float sqrtf_rn(float x) { return (float)sqrt((double)x); }

__device__ __forceinline__ void tf2x32(uint32_t k0, uint32_t k1,
                                       uint32_t x0, uint32_t x1,
                                       uint32_t& o0, uint32_t& o1) {
  uint32_t ks2 = k0 ^ k1 ^ 0x1BD11BDAu;
  x0 += k0; x1 += k1;
#define TFR(r) { x0 += x1; x1 = (x1 << (r)) | (x1 >> (32 - (r))); x1 ^= x0; }
  TFR(13) TFR(15) TFR(26) TFR(6)
  x0 += k1; x1 += ks2 + 1u;
  TFR(17) TFR(29) TFR(16) TFR(24)
  x0 += ks2; x1 += k0 + 2u;
  TFR(13) TFR(15) TFR(26) TFR(6)
  x0 += k0; x1 += k1 + 3u;
  TFR(17) TFR(29) TFR(16) TFR(24)
  x0 += k1; x1 += ks2 + 4u;
  TFR(13) TFR(15) TFR(26) TFR(6)
  x0 += ks2; x1 += k0 + 5u;
#undef TFR
  o0 = x0; o1 = x1;
}

// XLA CPU f32 log (Cephes/Pommier), NO FMA contraction.
__device__ __forceinline__ float cephes_logf_nofma(float u) {
  uint32_t bits = __float_as_uint(u);
  float e = (float)((int)(bits >> 23) - 0x7f) + 1.0f;
  float x = __uint_as_float((bits & 0x007fffffu) | 0x3f000000u);
  if (x < 0.707106781186547524f) {
    e -= 1.0f;
    x = addf(subf(x, 1.0f), x);
  } else {
    x = subf(x, 1.0f);
  }
  float z = mulf(x, x);
  float y = 7.0376836292e-2f;
  y = addf(mulf(y, x), -1.1514610310e-1f);
  y = addf(mulf(y, x),  1.1676998740e-1f);
  y = addf(mulf(y, x), -1.2420140846e-1f);
  y = addf(mulf(y, x),  1.4249322787e-1f);
  y = addf(mulf(y, x), -1.6668057665e-1f);
  y = addf(mulf(y, x),  2.0000714765e-1f);
  y = addf(mulf(y, x), -2.4999993993e-1f);
  y = addf(mulf(y, x),  3.3333331174e-1f);
  y = mulf(y, x);
  y = mulf(y, z);
  y = addf(y, mulf(e, -2.12194440e-4f));
  y = subf(y, mulf(z, 0.5f));
  x = addf(x, y);
  x = addf(x, mulf(e, 0.693359375f));
  return x;
}

// XLA CPU erfinv(f32), NO FMA.
__device__ __forceinline__ float xla_erfinv_nofma(float x) {
  float xx = mulf(x, x);
  float nx2 = -xx;
  float small_ = mulf(addf(mulf(-0.5f, nx2), 1.0f), nx2);
  float large_ = cephes_logf_nofma(addf(nx2, 1.0f));
  float l1p = (fabsf(nx2) < 1e-4f) ? small_ : large_;
  float w = -l1p;
  float p;
  if (w < 5.0f) {
    w = subf(w, 2.5f);
    p = 2.81022636e-08f;
    p = addf(mulf(p, w), 3.43273939e-07f);
    p = addf(mulf(p, w), -3.5233877e-06f);
    p = addf(mulf(p, w), -4.39150654e-06f);
    p = addf(mulf(p, w), 0.00021858087f);
    p = addf(mulf(p, w), -0.00125372503f);
    p = addf(mulf(p, w), -0.00417768164f);
    p = addf(mulf(p, w), 0.246640727f);
    p = addf(mulf(p, w), 1.50140941f);
  } else {
    w = subf(sqrtf_rn(w), 3.0f);
    p = -0.000200214257f;
    p = addf(mulf(p, w), 0.000100950558f);
    p = addf(mulf(p, w), 0.00134934322f);
    p = addf(mulf(p, w), -0.00367342844f);
    p = addf(mulf(p, w), 0.00573950773f);
    p = addf(mulf(p, w), -0.0076224613f);
    p = addf(mulf(p, w), 0.00943887047f);
    p = addf(mulf(p, w), 1.00167406f);
    p = addf(mulf(p, w), 2.83297682f);
  }
  return mulf(p, x);
}

__global__ void rng_kernel(float* __restrict__ alpha, float* __restrict__ beta) {
  int n = threadIdx.x;
  uint32_t ka0, ka1, kb0, kb1;
  tf2x32(0u, 1234u, 0u, 0u, ka0, ka1);
  tf2x32(0u, 1234u, 0u, 1u, kb0, kb1);
  const float lo = -0x1.fffffep-1f;
  if (n < 264) {
    uint32_t o0, o1;
    tf2x32(ka0, ka1, 0u, (uint32_t)n, o0, o1);
    uint32_t bits = o0 ^ o1;
    float f = __uint_as_float((bits >> 9) | 0x3f800000u) - 1.0f;
    float u = fmaxf(lo, addf(mulf(f, 2.0f), lo));
    alpha[n] = mulf(0x1.6a09e6p+0f, xla_erfinv_nofma(u));
  } else if (n < 268) {
    int m = n - 264;
    uint32_t o0, o1;
    tf2x32(kb0, kb1, 0u, (uint32_t)m, o0, o1);
    uint32_t bits = o0 ^ o1;
    float f = __uint_as_float((bits >> 9) | 0x3f800000u) - 1.0f;
    beta[m] = f;
  }
}

// Norms: scalar sequential, NO FMA (matches XLA CPU).
__global__ __launch_bounds__(256) void norm_kernel(
    const float* __restrict__ q, const float* __restrict__ k,
    float* __restrict__ qn, float* __restrict__ kn, float* __restrict__ Mv) {
  int b = blockIdx.x, tid = threadIdx.x;
  __shared__ float redq[256], redk[256];
  float mq = 0.0f, mk = 0.0f;
  for (int t = tid; t < QS; t += 256) {
    const float4* xq = (const float4*)(q + ((size_t)b * NTOK + 1 + t) * DIM);
    const float4* xk = (const float4*)(k + ((size_t)b * NTOK + 1 + t) * DIM);
    float sq = 0.0f, sk_ = 0.0f;
#pragma unroll
    for (int i = 0; i < 16; i++) {
      float4 a = xq[i], c = xk[i];
      sq = addf(sq, mulf(a.x, a.x)); sq = addf(sq, mulf(a.y, a.y));
      sq = addf(sq, mulf(a.z, a.z)); sq = addf(sq, mulf(a.w, a.w));
      sk_ = addf(sk_, mulf(c.x, c.x)); sk_ = addf(sk_, mulf(c.y, c.y));
      sk_ = addf(sk_, mulf(c.z, c.z)); sk_ = addf(sk_, mulf(c.w, c.w));
    }
    float nq = sqrtf_rn(sq), nk = sqrtf_rn(sk_);
    qn[(size_t)b * QS + t] = nq;
    kn[(size_t)b * QS + t] = nk;
    mq = fmaxf(mq, nq); mk = fmaxf(mk, nk);
  }
  redq[tid] = mq; redk[tid] = mk;
  __syncthreads();
  for (int s = 128; s > 0; s >>= 1) {
    if (tid < s) {
      redq[tid] = fmaxf(redq[tid], redq[tid + s]);
      redk[tid] = fmaxf(redk[tid], redk[tid + s]);
    }
    __syncthreads();
  }
  if (tid == 0) Mv[b] = addf(redq[0], redk[0]);
}

// Hash: ext NO-FMA; dot NO-FMA sequential; +beta.
__global__ __launch_bounds__(256) void hash_kernel(
    const float* __restrict__ q, const float* __restrict__ k,
    const float* __restrict__ qn, const float* __restrict__ kn,
    const float* __restrict__ Mv,
    const float* __restrict__ alpha, const float* __restrict__ beta,
    float* __restrict__ qh, float* __restrict__ kh) {
  __shared__ float as_[264];
  __shared__ float bs_[4];
  int tid = threadIdx.x;
  for (int i = tid; i < 268; i += 256) {
    if (i < 264) as_[i] = alpha[i]; else bs_[i - 264] = beta[i - 264];
  }
  __syncthreads();
  int t = blockIdx.x * 256 + tid;
  int b = blockIdx.y;
  bool isK = (blockIdx.z == 1);
  const float* x = (isK ? k : q) + ((size_t)b * NTOK + 1 + t) * DIM;
  float n = (isK ? kn : qn)[(size_t)b * QS + t];
  float m = Mv[b];
  float t0 = mulf(m, m);
  float t1 = mulf(n, n);
  float e2 = subf(t0, t1);
  float ext = sqrtf_rn(fmaxf(e2, 0.0f));
  float s0 = 0.f, s1 = 0.f, s2 = 0.f, s3 = 0.f;
  const float4* x4 = (const float4*)x;
#pragma unroll
  for (int d4 = 0; d4 < 16; d4++) {
    float4 xv = x4[d4];
    const float* ap = &as_[d4 * 16];
    s0 = addf(s0, mulf(xv.x, ap[0]));  s1 = addf(s1, mulf(xv.x, ap[1]));
    s2 = addf(s2, mulf(xv.x, ap[2]));  s3 = addf(s3, mulf(xv.x, ap[3]));
    s0 = addf(s0, mulf(xv.y, ap[4]));  s1 = addf(s1, mulf(xv.y, ap[5]));
    s2 = addf(s2, mulf(xv.y, ap[6]));  s3 = addf(s3, mulf(xv.y, ap[7]));
    s0 = addf(s0, mulf(xv.z, ap[8]));  s1 = addf(s1, mulf(xv.z, ap[9]));
    s2 = addf(s2, mulf(xv.z, ap[10])); s3 = addf(s3, mulf(xv.z, ap[11]));
    s0 = addf(s0, mulf(xv.w, ap[12])); s1 = addf(s1, mulf(xv.w, ap[13]));
    s2 = addf(s2, mulf(xv.w, ap[14])); s3 = addf(s3, mulf(xv.w, ap[15]));
  }
  int er = isK ? 65 : 64;
  s0 = addf(s0, mulf(ext, as_[er * 4 + 0]));
  s1 = addf(s1, mulf(ext, as_[er * 4 + 1]));
  s2 = addf(s2, mulf(ext, as_[er * 4 + 2]));
  s3 = addf(s3, mulf(ext, as_[er * 4 + 3]));
  float* dst = isK ? kh : qh;
  dst[((size_t)0 * BS + b) * QS + t] = addf(s0, bs_[0]);
  dst[((size_t)1 * BS + b) * QS + t] = addf(s1, bs_[1]);
  dst[((size_t)2 * BS + b) * QS + t] = addf(s2, bs_[2]);
  dst[((size_t)3 * BS + b) * QS + t] = addf(s3, bs_[3]);
}

// Bitonic sort of 4096 (f32 key, idx) pairs == JAX stable argsort.
__global__ __launch_bounds__(512) void sort_kernel(
    const float* __restrict__ qh, const float* __restrict__ kh,
    int* __restrict__ qpos, int* __restrict__ kpos) {
  __shared__ float key[QS];
  __shared__ int idx[QS];
  int sb = blockIdx.x;
  bool isK = sb >= NH * BS;
  int hb = isK ? sb - NH * BS : sb;
  const float* src = (isK ? kh : qh) + (size_t)hb * QS;
  int* dst = (isK ? kpos : qpos) + (size_t)hb * QS;
  int tid = threadIdx.x;
  for (int i = tid; i < QS; i += 512) { key[i] = src[i]; idx[i] = i; }
  __syncthreads();
  for (int kk = 2; kk <= QS; kk <<= 1) {
    for (int j = kk >> 1; j > 0; j >>= 1) {
      for (int n = tid; n < QS / 2; n += 512) {
        int i = ((n & ~(j - 1)) << 1) | (n & (j - 1));
        int l = i | j;
        bool up = ((i & kk) == 0);
        float a = key[i], c = key[l];
        int ia = idx[i], ic = idx[l];
        bool agtb = (a > c) || (a == c && ia > ic);
        if (agtb == up) { key[i] = c; key[l] = a; idx[i] = ic; idx[l] = ia; }
      }
      __syncthreads();
    }
  }
  for (int i = tid; i < QS; i += 512) dst[i] = idx[i];
}

// ---- optimized attention ----
// K staged in LDS, swizzled 16B blocks: word = row*64 + 4*(fd ^ (row&15)) + j.
#define LDSK(sk, row, d4) (*(const float4*)&(sk)[(row) * 64 + 4 * ((d4) ^ ((row) & 15))])

// Fused, 512 threads: rows 0..127 in exactly 4 iterations (no garbage slots);
// row 128 handled by a warp-0 epilogue. Q loads & V addresses scalarized via
// readfirstlane. LDS 50.6KB.
__global__ __launch_bounds__(512) void attn_fused(
    const float* __restrict__ q, const float* __restrict__ k, const float* __restrict__ v,
    const int* __restrict__ qpos, const int* __restrict__ kpos,
    float* __restrict__ logits, float* __restrict__ o, float* __restrict__ out) {
  int c = blockIdx.x, b = blockIdx.y, h = blockIdx.z;
  __shared__ __align__(16) float sk[CROWS * 64];
  __shared__ float4 pbuf[8][CROWS];
  __shared__ int qpos_s[128], kpos_s[128];
  int tid = threadIdx.x;
  size_t hb = (size_t)h * BS + b;
  if (tid < 128) {
    qpos_s[tid] = qpos[hb * QS + c * 128 + tid];
    kpos_s[tid] = kpos[hb * QS + c * 128 + tid];
  }
  __syncthreads();
  for (int idx = tid; idx < CROWS * 16; idx += 512) {
    int r = idx >> 4, fd = idx & 15;
    int g = (r == 0) ? 0 : (kpos_s[r - 1] + 1);
    float4 kv = *(const float4*)&k[((size_t)b * NTOK + g) * DIM + 4 * fd];
    *(float4*)&sk[r * 64 + 4 * (fd ^ (r & 15))] = kv;
  }
  __syncthreads();
  int wid = tid >> 6, lane = tid & 63;
  const float* vbase = v + (size_t)b * NTOK * DIM + lane;
  // main loop: rows 0..127, 4 iterations, bijective r = rb + 8i
  for (int rb = wid; rb < 128; rb += 32) {
    const float* qp[4];
#pragma unroll
    for (int i = 0; i < 4; i++) {
      int r = rb + 8 * i;
      int g = (r > 0) ? (qpos_s[r - 1] + 1) : 0;
      g = __builtin_amdgcn_readfirstlane(g);
      qp[i] = q + ((size_t)b * NTOK + g) * DIM;
    }
    float s0[4] = {0, 0, 0, 0}, s1[4] = {0, 0, 0, 0}, s2[4] = {0, 0, 0, 0};
#pragma unroll 4
    for (int d4 = 0; d4 < 16; d4++) {
      float4 k0 = LDSK(sk, lane, d4);
      float4 k1 = LDSK(sk, lane + 64, d4);
      float4 k2 = LDSK(sk, 128, d4);
#pragma unroll
      for (int i = 0; i < 4; i++) {
        float4 qv = *(const float4*)(qp[i] + 4 * d4);
        s0[i] = fmaf(qv.x, k0.x, s0[i]); s0[i] = fmaf(qv.y, k0.y, s0[i]);
        s0[i] = fmaf(qv.z, k0.z, s0[i]); s0[i] = fmaf(qv.w, k0.w, s0[i]);
        s1[i] = fmaf(qv.x, k1.x, s1[i]); s1[i] = fmaf(qv.y, k1.y, s1[i]);
        s1[i] = fmaf(qv.z, k1.z, s1[i]); s1[i] = fmaf(qv.w, k1.w, s1[i]);
        s2[i] = fmaf(qv.x, k2.x, s2[i]); s2[i] = fmaf(qv.y, k2.y, s2[i]);
        s2[i] = fmaf(qv.z, k2.z, s2[i]); s2[i] = fmaf(qv.w, k2.w, s2[i]);
      }
    }
    float Z[4];
#pragma unroll
    for (int i = 0; i < 4; i++) {
      float m = fmaxf(s0[i], s1[i]);
      for (int o2 = 32; o2 > 0; o2 >>= 1) m = fmaxf(m, __shfl_xor(m, o2, 64));
      m = fmaxf(m, s2[i]);
      s0[i] = expf(s0[i] - m); s1[i] = expf(s1[i] - m); s2[i] = expf(s2[i] - m);
      float zs = s0[i] + s1[i];
      for (int o2 = 32; o2 > 0; o2 >>= 1) zs += __shfl_xor(zs, o2, 64);
      Z[i] = zs + s2[i];
      int r = rb + 8 * i;
      if (r > 0 && lane == 0)
        logits[hb * QS + qpos_s[r - 1]] = m + logf(Z[i]);
    }
    pbuf[wid][lane]      = make_float4(s0[0], s0[1], s0[2], s0[3]);
    pbuf[wid][lane + 64] = make_float4(s1[0], s1[1], s1[2], s1[3]);
    if (lane == 0) pbuf[wid][128] = make_float4(s2[0], s2[1], s2[2], s2[3]);
    float4 acc0, acc1;
    {
      float4 pj = pbuf[wid][0];
      float vv = vbase[0];
      acc0.x = pj.x * vv; acc0.y = pj.y * vv; acc0.z = pj.z * vv; acc0.w = pj.w * vv;
      acc1 = make_float4(0.f, 0.f, 0.f, 0.f);
    }
    for (int j = 1; j < CROWS; j += 2) {
      float4 pa = pbuf[wid][j];
      int ga = kpos_s[j - 1] + 1;
      ga = __builtin_amdgcn_readfirstlane(ga);
      float va = vbase[(size_t)ga * DIM];
      acc0.x = fmaf(pa.x, va, acc0.x); acc0.y = fmaf(pa.y, va, acc0.y);
      acc0.z = fmaf(pa.z, va, acc0.z); acc0.w = fmaf(pa.w, va, acc0.w);
      float4 pb = pbuf[wid][j + 1];
      int gb = kpos_s[j] + 1;
      gb = __builtin_amdgcn_readfirstlane(gb);
      float vb = vbase[(size_t)gb * DIM];
      acc1.x = fmaf(pb.x, vb, acc1.x); acc1.y = fmaf(pb.y, vb, acc1.y);
      acc1.z = fmaf(pb.z, vb, acc1.z); acc1.w = fmaf(pb.w, vb, acc1.w);
    }
    float accs[4] = {acc0.x + acc1.x, acc0.y + acc1.y, acc0.z + acc1.z, acc0.w + acc1.w};
#pragma unroll
    for (int i = 0; i < 4; i++) {
      int r = rb + 8 * i;
      float outd = accs[i] / Z[i];
      if (r == 0) {
        atomicAdd(out + ((size_t)b * NTOK + 0) * DIM + lane, outd * (1.0f / 128.0f));
      } else {
        int t = qpos_s[r - 1];
        o[(hb * QS + t) * DIM + lane] = outd;
      }
    }
  }
  // epilogue: row 128 (token qpos_s[127]) by warp 0 only
  if (wid == 0) {
    int gq = qpos_s[127] + 1;
    gq = __builtin_amdgcn_readfirstlane(gq);
    const float* qp = q + ((size_t)b * NTOK + gq) * DIM;
    float t0 = 0.f, t1 = 0.f, t2 = 0.f;
#pragma unroll 4
    for (int d4 = 0; d4 < 16; d4++) {
      float4 k0 = LDSK(sk, lane, d4);
      float4 k1 = LDSK(sk, lane + 64, d4);
      float4 k2 = LDSK(sk, 128, d4);
      float4 qv = *(const float4*)(qp + 4 * d4);
      t0 = fmaf(qv.x, k0.x, t0); t0 = fmaf(qv.y, k0.y, t0);
      t0 = fmaf(qv.z, k0.z, t0); t0 = fmaf(qv.w, k0.w, t0);
      t1 = fmaf(qv.x, k1.x, t1); t1 = fmaf(qv.y, k1.y, t1);
      t1 = fmaf(qv.z, k1.z, t1); t1 = fmaf(qv.w, k1.w, t1);
      t2 = fmaf(qv.x, k2.x, t2); t2 = fmaf(qv.y, k2.y, t2);
      t2 = fmaf(qv.z, k2.z, t2); t2 = fmaf(qv.w, k2.w, t2);
    }
    float m = fmaxf(t0, t1);
    for (int o2 = 32; o2 > 0; o2 >>= 1) m = fmaxf(m, __shfl_xor(m, o2, 64));
    m = fmaxf(m, t2);
    t0 = expf(t0 - m); t1 = expf(t1 - m); t2 = expf(t2 - m);
    float zs = t0 + t1;
    for (int o2 = 32; o2 > 0; o2 >>= 1) zs += __shfl_xor(zs, o2, 64);
    float Z = zs + t2;
    if (lane == 0) logits[hb * QS + qpos_s[127]] = m + logf(Z);
    pbuf[0][lane].x = t0;
    pbuf[0][lane + 64].x = t1;
    if (lane == 0) pbuf[0][128].x = t2;
    float acc = 0.f;
    for (int j = 0; j < CROWS; j++) {
      float pj = pbuf[0][j].x;
      int g = (j == 0) ? 0 : (kpos_s[j - 1] + 1);
      g = __builtin_amdgcn_readfirstlane(g);
      acc = fmaf(pj, vbase[(size_t)g * DIM], acc);
    }
    o[(hb * QS + qpos_s[127]) * DIM + lane] = acc / Z;
  }
}

// Combine: out[token] = sum_h softmax_h(logits) * o_h
__global__ __launch_bounds__(256) void combine_kernel(
    const float* __restrict__ o, const float* __restrict__ logits,
    float* __restrict__ out) {
  int t = blockIdx.x * 4 + (threadIdx.x >> 6);
  int b = blockIdx.y;
  int d = threadIdx.x & 63;
  float l0 = logits[((size_t)0 * BS + b) * QS + t];
  float l1 = logits[((size_t)1 * BS + b) * QS + t];
  float l2 = logits[((size_t)2 * BS + b) * QS + t];
  float l3 = logits[((size_t)3 * BS + b) * QS + t];
  float mm = fmaxf(fmaxf(l0, l1), fmaxf(l2, l3));
  float e0 = expf(l0 - mm), e1 = expf(l1 - mm), e2 = expf(l2 - mm), e3 = expf(l3 - mm);
  float inv = 1.0f / (e0 + e1 + e2 + e3);
  float r;
  r = (e0 * inv) * o[(((size_t)0 * BS + b) * QS + t) * DIM + d];
  r = fmaf(e1 * inv, o[(((size_t)1 * BS + b) * QS + t) * DIM + d], r);
  r = fmaf(e2 * inv, o[(((size_t)2 * BS + b) * QS + t) * DIM + d], r);
  r = fmaf(e3 * inv, o[(((size_t)3 * BS + b) * QS + t) * DIM + d], r);
  out[((size_t)b * NTOK + 1 + t) * DIM + d] = r;
}

// ---- fallback two-pass (small ws) ----
__global__ __launch_bounds__(256) void attn1_opt(
    const float* __restrict__ q, const float* __restrict__ k,
    const int* __restrict__ qpos, const int* __restrict__ kpos,
    float* __restrict__ logits) {
  int c = blockIdx.x, b = blockIdx.y, h = blockIdx.z;
  __shared__ __align__(16) float sk[CROWS * 64];
  __shared__ int qpos_s[128], kpos_s[128];
  int tid = threadIdx.x;
  size_t hb = (size_t)h * BS + b;
  if (tid < 128) {
    qpos_s[tid] = qpos[hb * QS + c * 128 + tid];
    kpos_s[tid] = kpos[hb * QS + c * 128 + tid];
  }
  __syncthreads();
  for (int idx = tid; idx < CROWS * 16; idx += 256) {
    int r = idx >> 4, fd = idx & 15;
    int g = (r == 0) ? 0 : (kpos_s[r - 1] + 1);
    float4 kv = *(const float4*)&k[((size_t)b * NTOK + g) * DIM + 4 * fd];
    *(float4*)&sk[r * 64 + 4 * (fd ^ (r & 15))] = kv;
  }
  __syncthreads();
  int wid = tid >> 6, lane = tid & 63;
  for (int rb = wid; rb < CROWS; rb += 16) {
    const float* qp[4];
#pragma unroll
    for (int i = 0; i < 4; i++) {
      int r = rb + 4 * i;
      int g = 0;
      if (r < CROWS && r > 0) g = qpos_s[r - 1] + 1;
      qp[i] = q + ((size_t)b * NTOK + g) * DIM;
    }
    float s0[4] = {0, 0, 0, 0}, s1[4] = {0, 0, 0, 0}, s2[4] = {0, 0, 0, 0};
#pragma unroll 4
    for (int d4 = 0; d4 < 16; d4++) {
      float4 k0 = LDSK(sk, lane, d4);
      float4 k1 = LDSK(sk, lane + 64, d4);
      float4 k2 = LDSK(sk, 128, d4);
#pragma unroll
      for (int i = 0; i < 4; i++) {
        float4 qv = *(const float4*)(qp[i] + 4 * d4);
        s0[i] = fmaf(qv.x, k0.x, s0[i]); s0[i] = fmaf(qv.y, k0.y, s0[i]);
        s0[i] = fmaf(qv.z, k0.z, s0[i]); s0[i] = fmaf(qv.w, k0.w, s0[i]);
        s1[i] = fmaf(qv.x, k1.x, s1[i]); s1[i] = fmaf(qv.y, k1.y, s1[i]);
        s1[i] = fmaf(qv.z, k1.z, s1[i]); s1[i] = fmaf(qv.w, k1.w, s1[i]);
        s2[i] = fmaf(qv.x, k2.x, s2[i]); s2[i] = fmaf(qv.y, k2.y, s2[i]);
        s2[i] = fmaf(qv.z, k2.z, s2[i]); s2[i] = fmaf(qv.w, k2.w, s2[i]);
      }
    }
#pragma unroll
    for (int i = 0; i < 4; i++) {
      float m = fmaxf(s0[i], s1[i]);
      for (int o = 32; o > 0; o >>= 1) m = fmaxf(m, __shfl_xor(m, o, 64));
      m = fmaxf(m, s2[i]);
      float p0 = expf(s0[i] - m), p1 = expf(s1[i] - m), p2 = expf(s2[i] - m);
      float zs = p0 + p1;
      for (int o = 32; o > 0; o >>= 1) zs += __shfl_xor(zs, o, 64);
      float Z = zs + p2;
      float lse = m + logf(Z);
      int r = rb + 4 * i;
      if (r > 0 && r < CROWS && lane == 0) logits[hb * QS + qpos_s[r - 1]] = lse;
    }
  }
}

__global__ __launch_bounds__(256) void attn2_opt(
    const float* __restrict__ q, const float* __restrict__ k, const float* __restrict__ v,
    const int* __restrict__ qpos, const int* __restrict__ kpos,
    const float* __restrict__ logits, float* __restrict__ out) {
  int c = blockIdx.x, b = blockIdx.y, h = blockIdx.z;
  __shared__ __align__(16) float sk[CROWS * 64];
  __shared__ float4 pbuf[4][CROWS];
  __shared__ int qpos_s[128], kpos_s[128];
  int tid = threadIdx.x;
  size_t hb = (size_t)h * BS + b;
  if (tid < 128) {
    qpos_s[tid] = qpos[hb * QS + c * 128 + tid];
    kpos_s[tid] = kpos[hb * QS + c * 128 + tid];
  }
  __syncthreads();
  for (int idx = tid; idx < CROWS * 16; idx += 256) {
    int r = idx >> 4, fd = idx & 15;
    int g = (r == 0) ? 0 : (kpos_s[r - 1] + 1);
    float4 kv = *(const float4*)&k[((size_t)b * NTOK + g) * DIM + 4 * fd];
    *(float4*)&sk[r * 64 + 4 * (fd ^ (r & 15))] = kv;
  }
  __syncthreads();
  int wid = tid >> 6, lane = tid & 63;
  const float* vbase = v + (size_t)b * NTOK * DIM + lane;
  for (int rb = wid; rb < CROWS; rb += 16) {
    const float* qp[4];
#pragma unroll
    for (int i = 0; i < 4; i++) {
      int r = rb + 4 * i;
      int g = 0;
      if (r < CROWS && r > 0) g = qpos_s[r - 1] + 1;
      qp[i] = q + ((size_t)b * NTOK + g) * DIM;
    }
    float s0[4] = {0, 0, 0, 0}, s1[4] = {0, 0, 0, 0}, s2[4] = {0, 0, 0, 0};
#pragma unroll 4
    for (int d4 = 0; d4 < 16; d4++) {
      float4 k0 = LDSK(sk, lane, d4);
      float4 k1 = LDSK(sk, lane + 64, d4);
      float4 k2 = LDSK(sk, 128, d4);
#pragma unroll
      for (int i = 0; i < 4; i++) {
        float4 qv = *(const float4*)(qp[i] + 4 * d4);
        s0[i] = fmaf(qv.x, k0.x, s0[i]); s0[i] = fmaf(qv.y, k0.y, s0[i]);
        s0[i] = fmaf(qv.z, k0.z, s0[i]); s0[i] = fmaf(qv.w, k0.w, s0[i]);
        s1[i] = fmaf(qv.x, k1.x, s1[i]); s1[i] = fmaf(qv.y, k1.y, s1[i]);
        s1[i] = fmaf(qv.z, k1.z, s1[i]); s1[i] = fmaf(qv.w, k1.w, s1[i]);
        s2[i] = fmaf(qv.x, k2.x, s2[i]); s2[i] = fmaf(qv.y, k2.y, s2[i]);
        s2[i] = fmaf(qv.z, k2.z, s2[i]); s2[i] = fmaf(qv.w, k2.w, s2[i]);
      }
    }
    float Z[4];
#pragma unroll
    for (int i = 0; i < 4; i++) {
      float m = fmaxf(s0[i], s1[i]);
      for (int o = 32; o > 0; o >>= 1) m = fmaxf(m, __shfl_xor(m, o, 64));
      m = fmaxf(m, s2[i]);
      s0[i] = expf(s0[i] - m); s1[i] = expf(s1[i] - m); s2[i] = expf(s2[i] - m);
      float zs = s0[i] + s1[i];
      for (int o = 32; o > 0; o >>= 1) zs += __shfl_xor(zs, o, 64);
      Z[i] = zs + s2[i];
    }
    pbuf[wid][lane]      = make_float4(s0[0], s0[1], s0[2], s0[3]);
    pbuf[wid][lane + 64] = make_float4(s1[0], s1[1], s1[2], s1[3]);
    if (lane == 0) pbuf[wid][128] = make_float4(s2[0], s2[1], s2[2], s2[3]);
    float4 acc0, acc1;
    {
      float4 pj = pbuf[wid][0];
      float vv = vbase[0];
      acc0.x = pj.x * vv; acc0.y = pj.y * vv; acc0.z = pj.z * vv; acc0.w = pj.w * vv;
      acc1 = make_float4(0.f, 0.f, 0.f, 0.f);
    }
    for (int j = 1; j < CROWS; j += 2) {
      float4 pa = pbuf[wid][j];
      int ga = kpos_s[j - 1] + 1;
      float va = vbase[(size_t)ga * DIM];
      acc0.x = fmaf(pa.x, va, acc0.x); acc0.y = fmaf(pa.y, va, acc0.y);
      acc0.z = fmaf(pa.z, va, acc0.z); acc0.w = fmaf(pa.w, va, acc0.w);
      float4 pb = pbuf[wid][j + 1];
      int gb = kpos_s[j] + 1;
      float vb = vbase[(size_t)gb * DIM];
      acc1.x = fmaf(pb.x, vb, acc1.x); acc1.y = fmaf(pb.y, vb, acc1.y);
      acc1.z = fmaf(pb.z, vb, acc1.z); acc1.w = fmaf(pb.w, vb, acc1.w);
    }
    float accs[4] = {acc0.x + acc1.x, acc0.y + acc1.y, acc0.z + acc1.z, acc0.w + acc1.w};
#pragma unroll
    for (int i = 0; i < 4; i++) {
      int r = rb + 4 * i;
      if (r >= CROWS) break;
      float outd = accs[i] / Z[i];
      if (r == 0) {
        atomicAdd(out + ((size_t)b * NTOK + 0) * DIM + lane, outd * (1.0f / 128.0f));
      } else {
        int t = qpos_s[r - 1];
        float l0 = logits[((size_t)0 * BS + b) * QS + t];
        float l1 = logits[((size_t)1 * BS + b) * QS + t];
        float l2 = logits[((size_t)2 * BS + b) * QS + t];
        float l3 = logits[((size_t)3 * BS + b) * QS + t];
        float mm = fmaxf(fmaxf(l0, l1), fmaxf(l2, l3));
        float e0 = expf(l0 - mm), e1 = expf(l1 - mm), e2 = expf(l2 - mm), e3 = expf(l3 - mm);
        float eh = (h == 0) ? e0 : (h == 1) ? e1 : (h == 2) ? e2 : e3;
        float wgt = eh / (e0 + e1 + e2 + e3);
        atomicAdd(out + ((size_t)b * NTOK + 1 + t) * DIM + lane, outd * wgt);
      }
    }
  }
}

extern "C" void kernel_launch(void* const* d_in, const int* in_sizes, int n_in,
                              void* d_out, int out_size, void* d_ws, size_t ws_size,
                              hipStream_t stream) {
  const float* q = (const float*)d_in[0];
  const float* k = (const float*)d_in[1];
  const float* v = (const float*)d_in[2];
  float* out = (float*)d_out;
  char* ws = (char*)d_ws;

  float* alpha  = (float*)(ws + 0);
  float* beta   = (float*)(ws + 2048);
  float* qn     = (float*)(ws + 4096);
  float* kn     = qn + (size_t)BS * QS;
  float* Mv     = kn + (size_t)BS * QS;
  float* qh     = Mv + 256;
  float* kh     = qh + (size_t)NH * BS * QS;
  int* qpos     = (int*)(kh + (size_t)NH * BS * QS);
  int* kpos     = qpos + (size_t)NH * BS * QS;
  float* logits = (float*)(kpos + (size_t)NH * BS * QS);
  float* obuf   = logits + (size_t)NH * BS * QS;   // NH*BS*QS*DIM f32 = 134 MB
  size_t need_fused = (size_t)(obuf - (float*)ws) * 4 + (size_t)NH * BS * QS * DIM * 4;

  hipMemsetAsync(d_out, 0, (size_t)out_size * sizeof(float), stream);
  rng_kernel<<<1, 320, 0, stream>>>(alpha, beta);
  norm_kernel<<<BS, 256, 0, stream>>>(q, k, qn, kn, Mv);
  hash_kernel<<<dim3(QS / 256, BS, 2), 256, 0, stream>>>(q, k, qn, kn, Mv, alpha, beta, qh, kh);
  sort_kernel<<<NH * BS * 2, 512, 0, stream>>>(qh, kh, qpos, kpos);
  if (ws_size >= need_fused) {
    attn_fused<<<dim3(NC, BS, NH), 512, 0, stream>>>(q, k, v, qpos, kpos, logits, obuf, out);
    combine_kernel<<<dim3(QS / 4, BS), 256, 0, stream>>>(obuf, logits, out);
  } else {
    attn1_opt<<<dim3(NC, BS, NH), 256, 0, stream>>>(q, k, qpos, kpos, logits);
    attn2_opt<<<dim3(NC, BS, NH), 256, 0, stream>>>(q, k, v, qpos, kpos, logits, out);
  }
}

// Round 21
// 762.665 us; speedup vs baseline: 1.5407x; 1.5407x over previous
//
#include <hip/hip_runtime.h>
#include <stdint.h>
#include <math.h>

#define NH 4
#define BS 32
#define QS 4096
#define NTOK 4097
#define DIM 64
#define NC 32
#define CROWS 129

// --- contraction-proof f32 ops (hipcc defaults to -ffp-contract=fast) ---
__device__ __forceinline__ float mulf(float a, float b) { float r = a * b; asm volatile("" : "+v"(r)); return r; }
__device__ __forceinline__ float addf(float a, float b) { float r = a + b; asm volatile("" : "+v"(r)); return r; }
__device__ __forceinline__ float subf(float a, float b) { float r = a - b; asm volatile("" : "+v"(r)); return r; }
__device__ __forceinline__ float sqrtf_rn(float x) { return (float)sqrt((double)x); }

__device__ __forceinline__ void tf2x32(uint32_t k0, uint32_t k1,
                                       uint32_t x0, uint32_t x1,
                                       uint32_t& o0, uint32_t& o1) {
  uint32_t ks2 = k0 ^ k1 ^ 0x1BD11BDAu;
  x0 += k0; x1 += k1;
#define TFR(r) { x0 += x1; x1 = (x1 << (r)) | (x1 >> (32 - (r))); x1 ^= x0; }
  TFR(13) TFR(15) TFR(26) TFR(6)
  x0 += k1; x1 += ks2 + 1u;
  TFR(17) TFR(29) TFR(16) TFR(24)
  x0 += ks2; x1 += k0 + 2u;
  TFR(13) TFR(15) TFR(26) TFR(6)
  x0 += k0; x1 += k1 + 3u;
  TFR(17) TFR(29) TFR(16) TFR(24)
  x0 += k1; x1 += ks2 + 4u;
  TFR(13) TFR(15) TFR(26) TFR(6)
  x0 += ks2; x1 += k0 + 5u;
#undef TFR
  o0 = x0; o1 = x1;
}

// XLA CPU f32 log (Cephes/Pommier), NO FMA contraction.
__device__ __forceinline__ float cephes_logf_nofma(float u) {
  uint32_t bits = __float_as_uint(u);
  float e = (float)((int)(bits >> 23) - 0x7f) + 1.0f;
  float x = __uint_as_float((bits & 0x007fffffu) | 0x3f000000u);
  if (x < 0.707106781186547524f) {
    e -= 1.0f;
    x = addf(subf(x, 1.0f), x);
  } else {
    x = subf(x, 1.0f);
  }
  float z = mulf(x, x);
  float y = 7.0376836292e-2f;
  y = addf(mulf(y, x), -1.1514610310e-1f);
  y = addf(mulf(y, x),  1.1676998740e-1f);
  y = addf(mulf(y, x), -1.2420140846e-1f);
  y = addf(mulf(y, x),  1.4249322787e-1f);
  y = addf(mulf(y, x), -1.6668057665e-1f);
  y = addf(mulf(y, x),  2.0000714765e-1f);
  y = addf(mulf(y, x), -2.4999993993e-1f);
  y = addf(mulf(y, x),  3.3333331174e-1f);
  y = mulf(y, x);
  y = mulf(y, z);
  y = addf(y, mulf(e, -2.12194440e-4f));
  y = subf(y, mulf(z, 0.5f));
  x = addf(x, y);
  x = addf(x, mulf(e, 0.693359375f));
  return x;
}

// XLA CPU erfinv(f32), NO FMA.
__device__ __forceinline__ float xla_erfinv_nofma(float x) {
  float xx = mulf(x, x);
  float nx2 = -xx;
  float small_ = mulf(addf(mulf(-0.5f, nx2), 1.0f), nx2);
  float large_ = cephes_logf_nofma(addf(nx2, 1.0f));
  float l1p = (fabsf(nx2) < 1e-4f) ? small_ : large_;
  float w = -l1p;
  float p;
  if (w < 5.0f) {
    w = subf(w, 2.5f);
    p = 2.81022636e-08f;
    p = addf(mulf(p, w), 3.43273939e-07f);
    p = addf(mulf(p, w), -3.5233877e-06f);
    p = addf(mulf(p, w), -4.39150654e-06f);
    p = addf(mulf(p, w), 0.00021858087f);
    p = addf(mulf(p, w), -0.00125372503f);
    p = addf(mulf(p, w), -0.00417768164f);
    p = addf(mulf(p, w), 0.246640727f);
    p = addf(mulf(p, w), 1.50140941f);
  } else {
    w = subf(sqrtf_rn(w), 3.0f);
    p = -0.000200214257f;
    p = addf(mulf(p, w), 0.000100950558f);
    p = addf(mulf(p, w), 0.00134934322f);
    p = addf(mulf(p, w), -0.00367342844f);
    p = addf(mulf(p, w), 0.00573950773f);
    p = addf(mulf(p, w), -0.0076224613f);
    p = addf(mulf(p, w), 0.00943887047f);
    p = addf(mulf(p, w), 1.00167406f);
    p = addf(mulf(p, w), 2.83297682f);
  }
  return mulf(p, x);
}

__global__ void rng_kernel(float* __restrict__ alpha, float* __restrict__ beta) {
  int n = threadIdx.x;
  uint32_t ka0, ka1, kb0, kb1;
  tf2x32(0u, 1234u, 0u, 0u, ka0, ka1);
  tf2x32(0u, 1234u, 0u, 1u, kb0, kb1);
  const float lo = -0x1.fffffep-1f;
  if (n < 264) {
    uint32_t o0, o1;
    tf2x32(ka0, ka1, 0u, (uint32_t)n, o0, o1);
    uint32_t bits = o0 ^ o1;
    float f = __uint_as_float((bits >> 9) | 0x3f800000u) - 1.0f;
    float u = fmaxf(lo, addf(mulf(f, 2.0f), lo));
    alpha[n] = mulf(0x1.6a09e6p+0f, xla_erfinv_nofma(u));
  } else if (n < 268) {
    int m = n - 264;
    uint32_t o0, o1;
    tf2x32(kb0, kb1, 0u, (uint32_t)m, o0, o1);
    uint32_t bits = o0 ^ o1;
    float f = __uint_as_float((bits >> 9) | 0x3f800000u) - 1.0f;
    beta[m] = f;
  }
}

// Norms: scalar sequential, NO FMA (matches XLA CPU).
__global__ __launch_bounds__(256) void norm_kernel(
    const float* __restrict__ q, const float* __restrict__ k,
    float* __restrict__ qn, float* __restrict__ kn, float* __restrict__ Mv) {
  int b = blockIdx.x, tid = threadIdx.x;
  __shared__ float redq[256], redk[256];
  float mq = 0.0f, mk = 0.0f;
  for (int t = tid; t < QS; t += 256) {
    const float4* xq = (const float4*)(q + ((size_t)b * NTOK + 1 + t) * DIM);
    const float4* xk = (const float4*)(k + ((size_t)b * NTOK + 1 + t) * DIM);
    float sq = 0.0f, sk_ = 0.0f;
#pragma unroll
    for (int i = 0; i < 16; i++) {
      float4 a = xq[i], c = xk[i];
      sq = addf(sq, mulf(a.x, a.x)); sq = addf(sq, mulf(a.y, a.y));
      sq = addf(sq, mulf(a.z, a.z)); sq = addf(sq, mulf(a.w, a.w));
      sk_ = addf(sk_, mulf(c.x, c.x)); sk_ = addf(sk_, mulf(c.y, c.y));
      sk_ = addf(sk_, mulf(c.z, c.z)); sk_ = addf(sk_, mulf(c.w, c.w));
    }
    float nq = sqrtf_rn(sq), nk = sqrtf_rn(sk_);
    qn[(size_t)b * QS + t] = nq;
    kn[(size_t)b * QS + t] = nk;
    mq = fmaxf(mq, nq); mk = fmaxf(mk, nk);
  }
  redq[tid] = mq; redk[tid] = mk;
  __syncthreads();
  for (int s = 128; s > 0; s >>= 1) {
    if (tid < s) {
      redq[tid] = fmaxf(redq[tid], redq[tid + s]);
      redk[tid] = fmaxf(redk[tid], redk[tid + s]);
    }
    __syncthreads();
  }
  if (tid == 0) Mv[b] = addf(redq[0], redk[0]);
}

// Hash: ext NO-FMA; dot NO-FMA sequential; +beta.
__global__ __launch_bounds__(256) void hash_kernel(
    const float* __restrict__ q, const float* __restrict__ k,
    const float* __restrict__ qn, const float* __restrict__ kn,
    const float* __restrict__ Mv,
    const float* __restrict__ alpha, const float* __restrict__ beta,
    float* __restrict__ qh, float* __restrict__ kh) {
  __shared__ float as_[264];
  __shared__ float bs_[4];
  int tid = threadIdx.x;
  for (int i = tid; i < 268; i += 256) {
    if (i < 264) as_[i] = alpha[i]; else bs_[i - 264] = beta[i - 264];
  }
  __syncthreads();
  int t = blockIdx.x * 256 + tid;
  int b = blockIdx.y;
  bool isK = (blockIdx.z == 1);
  const float* x = (isK ? k : q) + ((size_t)b * NTOK + 1 + t) * DIM;
  float n = (isK ? kn : qn)[(size_t)b * QS + t];
  float m = Mv[b];
  float t0 = mulf(m, m);
  float t1 = mulf(n, n);
  float e2 = subf(t0, t1);
  float ext = sqrtf_rn(fmaxf(e2, 0.0f));
  float s0 = 0.f, s1 = 0.f, s2 = 0.f, s3 = 0.f;
  const float4* x4 = (const float4*)x;
#pragma unroll
  for (int d4 = 0; d4 < 16; d4++) {
    float4 xv = x4[d4];
    const float* ap = &as_[d4 * 16];
    s0 = addf(s0, mulf(xv.x, ap[0]));  s1 = addf(s1, mulf(xv.x, ap[1]));
    s2 = addf(s2, mulf(xv.x, ap[2]));  s3 = addf(s3, mulf(xv.x, ap[3]));
    s0 = addf(s0, mulf(xv.y, ap[4]));  s1 = addf(s1, mulf(xv.y, ap[5]));
    s2 = addf(s2, mulf(xv.y, ap[6]));  s3 = addf(s3, mulf(xv.y, ap[7]));
    s0 = addf(s0, mulf(xv.z, ap[8]));  s1 = addf(s1, mulf(xv.z, ap[9]));
    s2 = addf(s2, mulf(xv.z, ap[10])); s3 = addf(s3, mulf(xv.z, ap[11]));
    s0 = addf(s0, mulf(xv.w, ap[12])); s1 = addf(s1, mulf(xv.w, ap[13]));
    s2 = addf(s2, mulf(xv.w, ap[14])); s3 = addf(s3, mulf(xv.w, ap[15]));
  }
  int er = isK ? 65 : 64;
  s0 = addf(s0, mulf(ext, as_[er * 4 + 0]));
  s1 = addf(s1, mulf(ext, as_[er * 4 + 1]));
  s2 = addf(s2, mulf(ext, as_[er * 4 + 2]));
  s3 = addf(s3, mulf(ext, as_[er * 4 + 3]));
  float* dst = isK ? kh : qh;
  dst[((size_t)0 * BS + b) * QS + t] = addf(s0, bs_[0]);
  dst[((size_t)1 * BS + b) * QS + t] = addf(s1, bs_[1]);
  dst[((size_t)2 * BS + b) * QS + t] = addf(s2, bs_[2]);
  dst[((size_t)3 * BS + b) * QS + t] = addf(s3, bs_[3]);
}

// Bitonic sort of 4096 (f32 key, idx) pairs == JAX stable argsort.
__global__ __launch_bounds__(512) void sort_kernel(
    const float* __restrict__ qh, const float* __restrict__ kh,
    int* __restrict__ qpos, int* __restrict__ kpos) {
  __shared__ float key[QS];
  __shared__ int idx[QS];
  int sb = blockIdx.x;
  bool isK = sb >= NH * BS;
  int hb = isK ? sb - NH * BS : sb;
  const float* src = (isK ? kh : qh) + (size_t)hb * QS;
  int* dst = (isK ? kpos : qpos) + (size_t)hb * QS;
  int tid = threadIdx.x;
  for (int i = tid; i < QS; i += 512) { key[i] = src[i]; idx[i] = i; }
  __syncthreads();
  for (int kk = 2; kk <= QS; kk <<= 1) {
    for (int j = kk >> 1; j > 0; j >>= 1) {
      for (int n = tid; n < QS / 2; n += 512) {
        int i = ((n & ~(j - 1)) << 1) | (n & (j - 1));
        int l = i | j;
        bool up = ((i & kk) == 0);
        float a = key[i], c = key[l];
        int ia = idx[i], ic = idx[l];
        bool agtb = (a > c) || (a == c && ia > ic);
        if (agtb == up) { key[i] = c; key[l] = a; idx[i] = ic; idx[l] = ia; }
      }
      __syncthreads();
    }
  }
  for (int i = tid; i < QS; i += 512) dst[i] = idx[i];
}

// ---- optimized attention ----
// K staged in LDS, swizzled 16B blocks: word = row*64 + 4*(fd ^ (row&15)) + j.
#define LDSK(sk, row, d4) (*(const float4*)&(sk)[(row) * 64 + 4 * ((d4) ^ ((row) & 15))])

// Fused, 512 threads: rows 0..127 in exactly 4 iterations + warp-0 epilogue
// for row 128. No readfirstlane (compiler pipelines vector addresses better).
__global__ __launch_bounds__(512) void attn_fused(
    const float* __restrict__ q, const float* __restrict__ k, const float* __restrict__ v,
    const int* __restrict__ qpos, const int* __restrict__ kpos,
    float* __restrict__ logits, float* __restrict__ o, float* __restrict__ out) {
  int c = blockIdx.x, b = blockIdx.y, h = blockIdx.z;
  __shared__ __align__(16) float sk[CROWS * 64];
  __shared__ float4 pbuf[8][CROWS];
  __shared__ int qpos_s[128], kpos_s[128];
  int tid = threadIdx.x;
  size_t hb = (size_t)h * BS + b;
  if (tid < 128) {
    qpos_s[tid] = qpos[hb * QS + c * 128 + tid];
    kpos_s[tid] = kpos[hb * QS + c * 128 + tid];
  }
  __syncthreads();
  for (int idx = tid; idx < CROWS * 16; idx += 512) {
    int r = idx >> 4, fd = idx & 15;
    int g = (r == 0) ? 0 : (kpos_s[r - 1] + 1);
    float4 kv = *(const float4*)&k[((size_t)b * NTOK + g) * DIM + 4 * fd];
    *(float4*)&sk[r * 64 + 4 * (fd ^ (r & 15))] = kv;
  }
  __syncthreads();
  int wid = tid >> 6, lane = tid & 63;
  const float* vbase = v + (size_t)b * NTOK * DIM + lane;
  // main loop: rows 0..127, 4 iterations, bijective r = rb + 8i
  for (int rb = wid; rb < 128; rb += 32) {
    const float* qp[4];
#pragma unroll
    for (int i = 0; i < 4; i++) {
      int r = rb + 8 * i;
      int g = (r > 0) ? (qpos_s[r - 1] + 1) : 0;
      qp[i] = q + ((size_t)b * NTOK + g) * DIM;
    }
    float s0[4] = {0, 0, 0, 0}, s1[4] = {0, 0, 0, 0}, s2[4] = {0, 0, 0, 0};
#pragma unroll 4
    for (int d4 = 0; d4 < 16; d4++) {
      float4 k0 = LDSK(sk, lane, d4);
      float4 k1 = LDSK(sk, lane + 64, d4);
      float4 k2 = LDSK(sk, 128, d4);
#pragma unroll
      for (int i = 0; i < 4; i++) {
        float4 qv = *(const float4*)(qp[i] + 4 * d4);
        s0[i] = fmaf(qv.x, k0.x, s0[i]); s0[i] = fmaf(qv.y, k0.y, s0[i]);
        s0[i] = fmaf(qv.z, k0.z, s0[i]); s0[i] = fmaf(qv.w, k0.w, s0[i]);
        s1[i] = fmaf(qv.x, k1.x, s1[i]); s1[i] = fmaf(qv.y, k1.y, s1[i]);
        s1[i] = fmaf(qv.z, k1.z, s1[i]); s1[i] = fmaf(qv.w, k1.w, s1[i]);
        s2[i] = fmaf(qv.x, k2.x, s2[i]); s2[i] = fmaf(qv.y, k2.y, s2[i]);
        s2[i] = fmaf(qv.z, k2.z, s2[i]); s2[i] = fmaf(qv.w, k2.w, s2[i]);
      }
    }
    float Z[4];
#pragma unroll
    for (int i = 0; i < 4; i++) {
      float m = fmaxf(s0[i], s1[i]);
      for (int o2 = 32; o2 > 0; o2 >>= 1) m = fmaxf(m, __shfl_xor(m, o2, 64));
      m = fmaxf(m, s2[i]);
      s0[i] = expf(s0[i] - m); s1[i] = expf(s1[i] - m); s2[i] = expf(s2[i] - m);
      float zs = s0[i] + s1[i];
      for (int o2 = 32; o2 > 0; o2 >>= 1) zs += __shfl_xor(zs, o2, 64);
      Z[i] = zs + s2[i];
      int r = rb + 8 * i;
      if (r > 0 && lane == 0)
        logits[hb * QS + qpos_s[r - 1]] = m + logf(Z[i]);
    }
    pbuf[wid][lane]      = make_float4(s0[0], s0[1], s0[2], s0[3]);
    pbuf[wid][lane + 64] = make_float4(s1[0], s1[1], s1[2], s1[3]);
    if (lane == 0) pbuf[wid][128] = make_float4(s2[0], s2[1], s2[2], s2[3]);
    float4 acc0, acc1;
    {
      float4 pj = pbuf[wid][0];
      float vv = vbase[0];
      acc0.x = pj.x * vv; acc0.y = pj.y * vv; acc0.z = pj.z * vv; acc0.w = pj.w * vv;
      acc1 = make_float4(0.f, 0.f, 0.f, 0.f);
    }
    for (int j = 1; j < CROWS; j += 2) {
      float4 pa = pbuf[wid][j];
      int ga = kpos_s[j - 1] + 1;
      float va = vbase[(size_t)ga * DIM];
      acc0.x = fmaf(pa.x, va, acc0.x); acc0.y = fmaf(pa.y, va, acc0.y);
      acc0.z = fmaf(pa.z, va, acc0.z); acc0.w = fmaf(pa.w, va, acc0.w);
      float4 pb = pbuf[wid][j + 1];
      int gb = kpos_s[j] + 1;
      float vb = vbase[(size_t)gb * DIM];
      acc1.x = fmaf(pb.x, vb, acc1.x); acc1.y = fmaf(pb.y, vb, acc1.y);
      acc1.z = fmaf(pb.z, vb, acc1.z); acc1.w = fmaf(pb.w, vb, acc1.w);
    }
    float accs[4] = {acc0.x + acc1.x, acc0.y + acc1.y, acc0.z + acc1.z, acc0.w + acc1.w};
#pragma unroll
    for (int i = 0; i < 4; i++) {
      int r = rb + 8 * i;
      float outd = accs[i] / Z[i];
      if (r == 0) {
        atomicAdd(out + ((size_t)b * NTOK + 0) * DIM + lane, outd * (1.0f / 128.0f));
      } else {
        int t = qpos_s[r - 1];
        o[(hb * QS + t) * DIM + lane] = outd;
      }
    }
  }
  // epilogue: row 128 (token qpos_s[127]) by warp 0 only
  if (wid == 0) {
    int gq = qpos_s[127] + 1;
    const float* qp = q + ((size_t)b * NTOK + gq) * DIM;
    float t0 = 0.f, t1 = 0.f, t2 = 0.f;
#pragma unroll 4
    for (int d4 = 0; d4 < 16; d4++) {
      float4 k0 = LDSK(sk, lane, d4);
      float4 k1 = LDSK(sk, lane + 64, d4);
      float4 k2 = LDSK(sk, 128, d4);
      float4 qv = *(const float4*)(qp + 4 * d4);
      t0 = fmaf(qv.x, k0.x, t0); t0 = fmaf(qv.y, k0.y, t0);
      t0 = fmaf(qv.z, k0.z, t0); t0 = fmaf(qv.w, k0.w, t0);
      t1 = fmaf(qv.x, k1.x, t1); t1 = fmaf(qv.y, k1.y, t1);
      t1 = fmaf(qv.z, k1.z, t1); t1 = fmaf(qv.w, k1.w, t1);
      t2 = fmaf(qv.x, k2.x, t2); t2 = fmaf(qv.y, k2.y, t2);
      t2 = fmaf(qv.z, k2.z, t2); t2 = fmaf(qv.w, k2.w, t2);
    }
    float m = fmaxf(t0, t1);
    for (int o2 = 32; o2 > 0; o2 >>= 1) m = fmaxf(m, __shfl_xor(m, o2, 64));
    m = fmaxf(m, t2);
    t0 = expf(t0 - m); t1 = expf(t1 - m); t2 = expf(t2 - m);
    float zs = t0 + t1;
    for (int o2 = 32; o2 > 0; o2 >>= 1) zs += __shfl_xor(zs, o2, 64);
    float Z = zs + t2;
    if (lane == 0) logits[hb * QS + qpos_s[127]] = m + logf(Z);
    pbuf[0][lane].x = t0;
    pbuf[0][lane + 64].x = t1;
    if (lane == 0) pbuf[0][128].x = t2;
    float acc = 0.f;
    for (int j = 0; j < CROWS; j++) {
      float pj = pbuf[0][j].x;
      int g = (j == 0) ? 0 : (kpos_s[j - 1] + 1);
      acc = fmaf(pj, vbase[(size_t)g * DIM], acc);
    }
    o[(hb * QS + qpos_s[127]) * DIM + lane] = acc / Z;
  }
}

// Combine: out[token] = sum_h softmax_h(logits) * o_h
__global__ __launch_bounds__(256) void combine_kernel(
    const float* __restrict__ o, const float* __restrict__ logits,
    float* __restrict__ out) {
  int t = blockIdx.x * 4 + (threadIdx.x >> 6);
  int b = blockIdx.y;
  int d = threadIdx.x & 63;
  float l0 = logits[((size_t)0 * BS + b) * QS + t];
  float l1 = logits[((size_t)1 * BS + b) * QS + t];
  float l2 = logits[((size_t)2 * BS + b) * QS + t];
  float l3 = logits[((size_t)3 * BS + b) * QS + t];
  float mm = fmaxf(fmaxf(l0, l1), fmaxf(l2, l3));
  float e0 = expf(l0 - mm), e1 = expf(l1 - mm), e2 = expf(l2 - mm), e3 = expf(l3 - mm);
  float inv = 1.0f / (e0 + e1 + e2 + e3);
  float r;
  r = (e0 * inv) * o[(((size_t)0 * BS + b) * QS + t) * DIM + d];
  r = fmaf(e1 * inv, o[(((size_t)1 * BS + b) * QS + t) * DIM + d], r);
  r = fmaf(e2 * inv, o[(((size_t)2 * BS + b) * QS + t) * DIM + d], r);
  r = fmaf(e3 * inv, o[(((size_t)3 * BS + b) * QS + t) * DIM + d], r);
  out[((size_t)b * NTOK + 1 + t) * DIM + d] = r;
}

// ---- fallback two-pass (small ws) ----
__global__ __launch_bounds__(256) void attn1_opt(
    const float* __restrict__ q, const float* __restrict__ k,
    const int* __restrict__ qpos, const int* __restrict__ kpos,
    float* __restrict__ logits) {
  int c = blockIdx.x, b = blockIdx.y, h = blockIdx.z;
  __shared__ __align__(16) float sk[CROWS * 64];
  __shared__ int qpos_s[128], kpos_s[128];
  int tid = threadIdx.x;
  size_t hb = (size_t)h * BS + b;
  if (tid < 128) {
    qpos_s[tid] = qpos[hb * QS + c * 128 + tid];
    kpos_s[tid] = kpos[hb * QS + c * 128 + tid];
  }
  __syncthreads();
  for (int idx = tid; idx < CROWS * 16; idx += 256) {
    int r = idx >> 4, fd = idx & 15;
    int g = (r == 0) ? 0 : (kpos_s[r - 1] + 1);
    float4 kv = *(const float4*)&k[((size_t)b * NTOK + g) * DIM + 4 * fd];
    *(float4*)&sk[r * 64 + 4 * (fd ^ (r & 15))] = kv;
  }
  __syncthreads();
  int wid = tid >> 6, lane = tid & 63;
  for (int rb = wid; rb < CROWS; rb += 16) {
    const float* qp[4];
#pragma unroll
    for (int i = 0; i < 4; i++) {
      int r = rb + 4 * i;
      int g = 0;
      if (r < CROWS && r > 0) g = qpos_s[r - 1] + 1;
      qp[i] = q + ((size_t)b * NTOK + g) * DIM;
    }
    float s0[4] = {0, 0, 0, 0}, s1[4] = {0, 0, 0, 0}, s2[4] = {0, 0, 0, 0};
#pragma unroll 4
    for (int d4 = 0; d4 < 16; d4++) {
      float4 k0 = LDSK(sk, lane, d4);
      float4 k1 = LDSK(sk, lane + 64, d4);
      float4 k2 = LDSK(sk, 128, d4);
#pragma unroll
      for (int i = 0; i < 4; i++) {
        float4 qv = *(const float4*)(qp[i] + 4 * d4);
        s0[i] = fmaf(qv.x, k0.x, s0[i]); s0[i] = fmaf(qv.y, k0.y, s0[i]);
        s0[i] = fmaf(qv.z, k0.z, s0[i]); s0[i] = fmaf(qv.w, k0.w, s0[i]);
        s1[i] = fmaf(qv.x, k1.x, s1[i]); s1[i] = fmaf(qv.y, k1.y, s1[i]);
        s1[i] = fmaf(qv.z, k1.z, s1[i]); s1[i] = fmaf(qv.w, k1.w, s1[i]);
        s2[i] = fmaf(qv.x, k2.x, s2[i]); s2[i] = fmaf(qv.y, k2.y, s2[i]);
        s2[i] = fmaf(qv.z, k2.z, s2[i]); s2[i] = fmaf(qv.w, k2.w, s2[i]);
      }
    }
#pragma unroll
    for (int i = 0; i < 4; i++) {
      float m = fmaxf(s0[i], s1[i]);
      for (int o = 32; o > 0; o >>= 1) m = fmaxf(m, __shfl_xor(m, o, 64));
      m = fmaxf(m, s2[i]);
      float p0 = expf(s0[i] - m), p1 = expf(s1[i] - m), p2 = expf(s2[i] - m);
      float zs = p0 + p1;
      for (int o = 32; o > 0; o >>= 1) zs += __shfl_xor(zs, o, 64);
      float Z = zs + p2;
      float lse = m + logf(Z);
      int r = rb + 4 * i;
      if (r > 0 && r < CROWS && lane == 0) logits[hb * QS + qpos_s[r - 1]] = lse;
    }
  }
}

__global__ __launch_bounds__(256) void attn2_opt(
    const float* __restrict__ q, const float* __restrict__ k, const float* __restrict__ v,
    const int* __restrict__ qpos, const int* __restrict__ kpos,
    const float* __restrict__ logits, float* __restrict__ out) {
  int c = blockIdx.x, b = blockIdx.y, h = blockIdx.z;
  __shared__ __align__(16) float sk[CROWS * 64];
  __shared__ float4 pbuf[4][CROWS];
  __shared__ int qpos_s[128], kpos_s[128];
  int tid = threadIdx.x;
  size_t hb = (size_t)h * BS + b;
  if (tid < 128) {
    qpos_s[tid] = qpos[hb * QS + c * 128 + tid];
    kpos_s[tid] = kpos[hb * QS + c * 128 + tid];
  }
  __syncthreads();
  for (int idx = tid; idx < CROWS * 16; idx += 256) {
    int r = idx >> 4, fd = idx & 15;
    int g = (r == 0) ? 0 : (kpos_s[r - 1] + 1);
    float4 kv = *(const float4*)&k[((size_t)b * NTOK + g) * DIM + 4 * fd];
    *(float4*)&sk[r * 64 + 4 * (fd ^ (r & 15))] = kv;
  }
  __syncthreads();
  int wid = tid >> 6, lane = tid & 63;
  const float* vbase = v + (size_t)b * NTOK * DIM + lane;
  for (int rb = wid; rb < CROWS; rb += 16) {
    const float* qp[4];
#pragma unroll
    for (int i = 0; i < 4; i++) {
      int r = rb + 4 * i;
      int g = 0;
      if (r < CROWS && r > 0) g = qpos_s[r - 1] + 1;
      qp[i] = q + ((size_t)b * NTOK + g) * DIM;
    }
    float s0[4] = {0, 0, 0, 0}, s1[4] = {0, 0, 0, 0}, s2[4] = {0, 0, 0, 0};
#pragma unroll 4
    for (int d4 = 0; d4 < 16; d4++) {
      float4 k0 = LDSK(sk, lane, d4);
      float4 k1 = LDSK(sk, lane + 64, d4);
      float4 k2 = LDSK(sk, 128, d4);
#pragma unroll
      for (int i = 0; i < 4; i++) {
        float4 qv = *(const float4*)(qp[i] + 4 * d4);
        s0[i] = fmaf(qv.x, k0.x, s0[i]); s0[i] = fmaf(qv.y, k0.y, s0[i]);
        s0[i] = fmaf(qv.z, k0.z, s0[i]); s0[i] = fmaf(qv.w, k0.w, s0[i]);
        s1[i] = fmaf(qv.x, k1.x, s1[i]); s1[i] = fmaf(qv.y, k1.y, s1[i]);
        s1[i] = fmaf(qv.z, k1.z, s1[i]); s1[i] = fmaf(qv.w, k1.w, s1[i]);
        s2[i] = fmaf(qv.x, k2.x, s2[i]); s2[i] = fmaf(qv.y, k2.y, s2[i]);
        s2[i] = fmaf(qv.z, k2.z, s2[i]); s2[i] = fmaf(qv.w, k2.w, s2[i]);
      }
    }
    float Z[4];
#pragma unroll
    for (int i = 0; i < 4; i++) {
      float m = fmaxf(s0[i], s1[i]);
      for (int o = 32; o > 0; o >>= 1) m = fmaxf(m, __shfl_xor(m, o, 64));
      m = fmaxf(m, s2[i]);
      s0[i] = expf(s0[i] - m); s1[i] = expf(s1[i] - m); s2[i] = expf(s2[i] - m);
      float zs = s0[i] + s1[i];
      for (int o = 32; o > 0; o >>= 1) zs += __shfl_xor(zs, o, 64);
      Z[i] = zs + s2[i];
    }
    pbuf[wid][lane]      = make_float4(s0[0], s0[1], s0[2], s0[3]);
    pbuf[wid][lane + 64] = make_float4(s1[0], s1[1], s1[2], s1[3]);
    if (lane == 0) pbuf[wid][128] = make_float4(s2[0], s2[1], s2[2], s2[3]);
    float4 acc0, acc1;
    {
      float4 pj = pbuf[wid][0];
      float vv = vbase[0];
      acc0.x = pj.x * vv; acc0.y = pj.y * vv; acc0.z = pj.z * vv; acc0.w = pj.w * vv;
      acc1 = make_float4(0.f, 0.f, 0.f, 0.f);
    }
    for (int j = 1; j < CROWS; j += 2) {
      float4 pa = pbuf[wid][j];
      int ga = kpos_s[j - 1] + 1;
      float va = vbase[(size_t)ga * DIM];
      acc0.x = fmaf(pa.x, va, acc0.x); acc0.y = fmaf(pa.y, va, acc0.y);
      acc0.z = fmaf(pa.z, va, acc0.z); acc0.w = fmaf(pa.w, va, acc0.w);
      float4 pb = pbuf[wid][j + 1];
      int gb = kpos_s[j] + 1;
      float vb = vbase[(size_t)gb * DIM];
      acc1.x = fmaf(pb.x, vb, acc1.x); acc1.y = fmaf(pb.y, vb, acc1.y);
      acc1.z = fmaf(pb.z, vb, acc1.z); acc1.w = fmaf(pb.w, vb, acc1.w);
    }
    float accs[4] = {acc0.x + acc1.x, acc0.y + acc1.y, acc0.z + acc1.z, acc0.w + acc1.w};
#pragma unroll
    for (int i = 0; i < 4; i++) {
      int r = rb + 4 * i;
      if (r >= CROWS) break;
      float outd = accs[i] / Z[i];
      if (r == 0) {
        atomicAdd(out + ((size_t)b * NTOK + 0) * DIM + lane, outd * (1.0f / 128.0f));
      } else {
        int t = qpos_s[r - 1];
        float l0 = logits[((size_t)0 * BS + b) * QS + t];
        float l1 = logits[((size_t)1 * BS + b) * QS + t];
        float l2 = logits[((size_t)2 * BS + b) * QS + t];
        float l3 = logits[((size_t)3 * BS + b) * QS + t];
        float mm = fmaxf(fmaxf(l0, l1), fmaxf(l2, l3));
        float e0 = expf(l0 - mm), e1 = expf(l1 - mm), e2 = expf(l2 - mm), e3 = expf(l3 - mm);
        float eh = (h == 0) ? e0 : (h == 1) ? e1 : (h == 2) ? e2 : e3;
        float wgt = eh / (e0 + e1 + e2 + e3);
        atomicAdd(out + ((size_t)b * NTOK + 1 + t) * DIM + lane, outd * wgt);
      }
    }
  }
}

extern "C" void kernel_launch(void* const* d_in, const int* in_sizes, int n_in,
                              void* d_out, int out_size, void* d_ws, size_t ws_size,
                              hipStream_t stream) {
  const float* q = (const float*)d_in[0];
  const float* k = (const float*)d_in[1];
  const float* v = (const float*)d_in[2];
  float* out = (float*)d_out;
  char* ws = (char*)d_ws;

  float* alpha  = (float*)(ws + 0);
  float* beta   = (float*)(ws + 2048);
  float* qn     = (float*)(ws + 4096);
  float* kn     = qn + (size_t)BS * QS;
  float* Mv     = kn + (size_t)BS * QS;
  float* qh     = Mv + 256;
  float* kh     = qh + (size_t)NH * BS * QS;
  int* qpos     = (int*)(kh + (size_t)NH * BS * QS);
  int* kpos     = qpos + (size_t)NH * BS * QS;
  float* logits = (float*)(kpos + (size_t)NH * BS * QS);
  float* obuf   = logits + (size_t)NH * BS * QS;   // NH*BS*QS*DIM f32 = 134 MB
  size_t need_fused = (size_t)(obuf - (float*)ws) * 4 + (size_t)NH * BS * QS * DIM * 4;

  hipMemsetAsync(d_out, 0, (size_t)out_size * sizeof(float), stream);
  rng_kernel<<<1, 320, 0, stream>>>(alpha, beta);
  norm_kernel<<<BS, 256, 0, stream>>>(q, k, qn, kn, Mv);
  hash_kernel<<<dim3(QS / 256, BS, 2), 256, 0, stream>>>(q, k, qn, kn, Mv, alpha, beta, qh, kh);
  sort_kernel<<<NH * BS * 2, 512, 0, stream>>>(qh, kh, qpos, kpos);
  if (ws_size >= need_fused) {
    attn_fused<<<dim3(NC, BS, NH), 512, 0, stream>>>(q, k, v, qpos, kpos, logits, obuf, out);
    combine_kernel<<<dim3(QS / 4, BS), 256, 0, stream>>>(obuf, logits, out);
  } else {
    attn1_opt<<<dim3(NC, BS, NH), 256, 0, stream>>>(q, k, qpos, kpos, logits);
    attn2_opt<<<dim3(NC, BS, NH), 256, 0, stream>>>(q, k, v, qpos, kpos, logits, out);
  }
}